// Round 1
// baseline (2993.031 us; speedup 1.0000x reference)
//
#include <hip/hip_runtime.h>

// Problem constants
#define Hh    100
#define Ww    152
#define Pp    15200        // H*W
#define Cc    256
#define NBATCH 8
#define NC1   81
#define NCLS  80
#define KTOP  100

// conv tile
#define BM 128
#define BN 128

// ---------------------------------------------------------------------------
// Kernel 1: 3x3 conv (SAME, stride 1) + bias + ReLU.
// Implicit GEMM: 128 out-ch x 128 flat pixels per block, BK=8 in-ch chunks,
// 9 taps inner. Per-thread 8x8 accumulators (ty: k-group, tx: pixel-group).
// B tile: 4 full rows (y0-1..y0+2) x 152, stored flat per channel so shifted
// reads stay contiguous & 16B aligned. x-borders fixed by hoisted predicates.
// ---------------------------------------------------------------------------
__global__ __launch_bounds__(256, 2)
void conv3x3_relu(const float* __restrict__ x, const float* __restrict__ w1,
                  const float* __restrict__ b1, float* __restrict__ hid)
{
    __shared__ float As[72 * 128];      // [ct = c_l*9+tap][k]
    __shared__ float Bs[4 + 8 * 608];   // 4-float front pad; [c_l][ry*152 + col]

    const int tid = threadIdx.x;
    const int p0  = blockIdx.x * BN;
    const int k0  = blockIdx.y * BM;
    const int n   = blockIdx.z;
    const int y0  = p0 / Ww;
    const int tx  = tid & 15;           // pixel group (8 px each)
    const int ty  = tid >> 4;           // out-channel group (8 k each)
    const int pl  = (p0 - y0 * Ww) + tx * 8;  // flat offset rel. to row y0 start

    // x-coordinate of this thread's first pixel; border slots
    const int xs   = (p0 + tx * 8) % Ww;
    const int j0   = (Ww - xs) % Ww;    // slot with x==0   (valid if <8)
    const int j151 = (Ww - 1) - xs;     // slot with x==151 (valid if <8)
    bool z0[8], z1[8];
#pragma unroll
    for (int j = 0; j < 8; ++j) { z0[j] = (j == j0); z1[j] = (j == j151); }

    float acc[8][8];
#pragma unroll
    for (int a = 0; a < 8; ++a)
#pragma unroll
        for (int b = 0; b < 8; ++b) acc[a][b] = 0.f;

    const size_t xbase = (size_t)n * Cc * Pp;

#pragma unroll 1
    for (int c0 = 0; c0 < Cc; c0 += 8) {
        // ---- stage A: w1[k0..k0+127][c0..c0+7][3][3]  (2304 float4) ----
#pragma unroll
        for (int i = 0; i < 9; ++i) {
            int q = i * 256 + tid;
            int k = q / 18;
            int f = q - k * 18;
            float4 v = *(const float4*)(w1 + (size_t)(k0 + k) * 2304 + c0 * 9 + f * 4);
            int ct = f * 4;
            As[(ct + 0) * 128 + k] = v.x;
            As[(ct + 1) * 128 + k] = v.y;
            As[(ct + 2) * 128 + k] = v.z;
            As[(ct + 3) * 128 + k] = v.w;
        }
        // ---- stage B: rows y0-1..y0+2, 152 cols, 8 channels (1216 float4) ----
#pragma unroll
        for (int i = 0; i < 5; ++i) {
            int q = i * 256 + tid;
            if (q < 1216) {
                int cr = q / 38;
                int f  = q - cr * 38;
                int cl = cr >> 2;
                int ry = cr & 3;
                int y  = y0 - 1 + ry;
                float4 v = make_float4(0.f, 0.f, 0.f, 0.f);
                if ((unsigned)y < (unsigned)Hh)
                    v = *(const float4*)(x + xbase + (size_t)(c0 + cl) * Pp + y * Ww + f * 4);
                *(float4*)(&Bs[4] + cl * 608 + ry * 152 + f * 4) = v;
            }
        }
        __syncthreads();

        // ---- compute ----
        for (int cl = 0; cl < 8; ++cl) {
#pragma unroll
            for (int dy = 0; dy < 3; ++dy) {
                // 16-float window covering all 3 dx shifts of this row
                const float* bp = &Bs[4] + cl * 608 + pl + dy * 152 - 4;  // 16B aligned
                float4 q0 = *(const float4*)(bp);
                float4 q1 = *(const float4*)(bp + 4);
                float4 q2 = *(const float4*)(bp + 8);
                float4 q3 = *(const float4*)(bp + 12);
                float r[16] = {q0.x,q0.y,q0.z,q0.w, q1.x,q1.y,q1.z,q1.w,
                               q2.x,q2.y,q2.z,q2.w, q3.x,q3.y,q3.z,q3.w};
                const float* ap = &As[(cl * 9 + dy * 3) * 128 + ty * 8];
#pragma unroll
                for (int dx = 0; dx < 3; ++dx) {
                    float4 a0 = *(const float4*)(ap + dx * 128);
                    float4 a1 = *(const float4*)(ap + dx * 128 + 4);
                    float a[8] = {a0.x,a0.y,a0.z,a0.w, a1.x,a1.y,a1.z,a1.w};
                    float b[8];
#pragma unroll
                    for (int j = 0; j < 8; ++j) {
                        float v = r[3 + j + dx];
                        if (dx == 0) v = z0[j] ? 0.f : v;   // x==0  : left neighbor OOB
                        if (dx == 2) v = z1[j] ? 0.f : v;   // x==151: right neighbor OOB
                        b[j] = v;
                    }
#pragma unroll
                    for (int ko = 0; ko < 8; ++ko)
#pragma unroll
                        for (int j = 0; j < 8; ++j)
                            acc[ko][j] = fmaf(a[ko], b[j], acc[ko][j]);
                }
            }
        }
        __syncthreads();
    }

    // ---- epilogue: bias + relu, float4 stores ----
    if (p0 + tx * 8 < Pp) {
#pragma unroll
        for (int ko = 0; ko < 8; ++ko) {
            int k = k0 + ty * 8 + ko;
            float bias = b1[k];
            float4 v0, v1;
            v0.x = fmaxf(acc[ko][0] + bias, 0.f);
            v0.y = fmaxf(acc[ko][1] + bias, 0.f);
            v0.z = fmaxf(acc[ko][2] + bias, 0.f);
            v0.w = fmaxf(acc[ko][3] + bias, 0.f);
            v1.x = fmaxf(acc[ko][4] + bias, 0.f);
            v1.y = fmaxf(acc[ko][5] + bias, 0.f);
            v1.z = fmaxf(acc[ko][6] + bias, 0.f);
            v1.w = fmaxf(acc[ko][7] + bias, 0.f);
            float* dst = hid + ((size_t)n * Cc + k) * Pp + p0 + tx * 8;
            *(float4*)dst = v0;
            *(float4*)(dst + 4) = v1;
        }
    }
}

// ---------------------------------------------------------------------------
// Kernel 2: 1x1 conv to 81 logits + bias, softmax over 81, argmax over 80.
// One thread per pixel; w2 staged (transposed, j-padded to 84) in LDS so the
// per-c inner loop reads 21 broadcast float4s. Writes logits (output 2) and
// per-pixel (p = prob of argmax class, c = argmax class) maps.
// ---------------------------------------------------------------------------
__global__ __launch_bounds__(256, 2)
void conv1x1_softmax(const float* __restrict__ hid, const float* __restrict__ w2,
                     const float* __restrict__ b2, float* __restrict__ logits,
                     float* __restrict__ pmap, int* __restrict__ cmap)
{
    __shared__ float w2s[64 * 84];   // [c_l][j], j padded 81->84 with zeros
    const int tid = threadIdx.x;
    const int p   = blockIdx.x * 256 + tid;
    const int n   = blockIdx.y;
    const bool valid = (p < Pp);
    const int psafe = valid ? p : 0;

    float acc[84];
#pragma unroll
    for (int j = 0; j < 84; ++j) acc[j] = 0.f;

#pragma unroll 1
    for (int c0 = 0; c0 < Cc; c0 += 64) {
        __syncthreads();
#pragma unroll
        for (int i = 0; i < 21; ++i) {   // 21*256 == 64*84
            int q  = i * 256 + tid;
            int cl = q / 84;
            int j  = q - cl * 84;
            float v = 0.f;
            if (j < NC1) v = w2[j * 256 + c0 + cl];
            w2s[cl * 84 + j] = v;
        }
        __syncthreads();

        const float* hptr = hid + ((size_t)n * Cc + c0) * Pp + psafe;
#pragma unroll 2
        for (int cl = 0; cl < 64; ++cl) {
            float h = hptr[(size_t)cl * Pp];
            const float4* wrow = (const float4*)(&w2s[cl * 84]);
#pragma unroll
            for (int f = 0; f < 21; ++f) {
                float4 wv = wrow[f];
                acc[f * 4 + 0] = fmaf(wv.x, h, acc[f * 4 + 0]);
                acc[f * 4 + 1] = fmaf(wv.y, h, acc[f * 4 + 1]);
                acc[f * 4 + 2] = fmaf(wv.z, h, acc[f * 4 + 2]);
                acc[f * 4 + 3] = fmaf(wv.w, h, acc[f * 4 + 3]);
            }
        }
    }

    if (valid) {
#pragma unroll
        for (int j = 0; j < NC1; ++j) acc[j] += b2[j];

        float* lp = logits + (size_t)n * NC1 * Pp + p;
#pragma unroll
        for (int j = 0; j < NC1; ++j) lp[(size_t)j * Pp] = acc[j];

        float m = -3.4e38f;
#pragma unroll
        for (int j = 0; j < NC1; ++j) m = fmaxf(m, acc[j]);
        float s = 0.f;
#pragma unroll
        for (int j = 0; j < NC1; ++j) s += __expf(acc[j] - m);
        float best = -3.4e38f; int bi = 0;
#pragma unroll
        for (int j = 0; j < NCLS; ++j) {   // first occurrence wins (strict >)
            if (acc[j] > best) { best = acc[j]; bi = j; }
        }
        pmap[n * Pp + p] = __expf(best - m) / s;
        cmap[n * Pp + p] = bi;
    }
}

// ---------------------------------------------------------------------------
// Kernel 3: score = p + 1{local max}. After one-hot masking only channel c is
// nonzero at each pixel, so the 3x3/81-channel local-max reduces to: no
// 8-neighbor with the same class and strictly larger p (and p >= eps).
// ---------------------------------------------------------------------------
__global__ void local_score(const float* __restrict__ pmap, const int* __restrict__ cmap,
                            float* __restrict__ scores)
{
    int p = blockIdx.x * 256 + threadIdx.x;
    int n = blockIdx.y;
    if (p >= Pp) return;
    int base = n * Pp;
    float pv = pmap[base + p];
    int   c  = cmap[base + p];
    int y = p / Ww, xc = p - y * Ww;
    bool ok = (pv >= 1e-6f);
#pragma unroll
    for (int dy = -1; dy <= 1; ++dy)
#pragma unroll
        for (int dx = -1; dx <= 1; ++dx) {
            if (dy == 0 && dx == 0) continue;
            int yy = y + dy, xx = xc + dx;
            if (yy >= 0 && yy < Hh && xx >= 0 && xx < Ww) {
                int q = base + yy * Ww + xx;
                if (cmap[q] == c && pmap[q] > pv) ok = false;
            }
        }
    scores[base + p] = pv + (ok ? 1.f : 0.f);
}

// ---------------------------------------------------------------------------
// Kernel 4: per-batch top-100 (lax.top_k semantics: value desc, index asc on
// ties) via 100 iterations of block-wide max over LDS-resident scores, using
// composite key (float_bits << 32) | (0xFFFF - idx). Then gathers x / pos.
// ---------------------------------------------------------------------------
__global__ __launch_bounds__(256)
void topk_gather(const float* __restrict__ scores, const float* __restrict__ x,
                 const float* __restrict__ pos, float* __restrict__ oprop,
                 float* __restrict__ opos)
{
    __shared__ float sv[Pp];                 // 60.8 KB
    __shared__ int sidx[KTOP];
    __shared__ unsigned long long red[4];
    const int tid = threadIdx.x;
    const int n   = blockIdx.x;

    for (int i = tid; i < Pp; i += 256) sv[i] = scores[n * Pp + i];
    __syncthreads();

    for (int it = 0; it < KTOP; ++it) {
        unsigned long long best = 0ull;
        for (int i = tid; i < Pp; i += 256) {
            unsigned fb = __float_as_uint(sv[i]);   // scores > 0 => monotone bits
            unsigned long long key =
                ((unsigned long long)fb << 32) | (unsigned)(0xFFFF - i);
            best = key > best ? key : best;
        }
#pragma unroll
        for (int off = 32; off > 0; off >>= 1) {
            unsigned long long o = __shfl_down(best, off, 64);
            best = o > best ? o : best;
        }
        if ((tid & 63) == 0) red[tid >> 6] = best;
        __syncthreads();
        if (tid == 0) {
            unsigned long long b = red[0];
            b = red[1] > b ? red[1] : b;
            b = red[2] > b ? red[2] : b;
            b = red[3] > b ? red[3] : b;
            int idx = 0xFFFF - (int)(b & 0xFFFFFFFFull);
            sidx[it] = idx;
            sv[idx]  = 0.f;                  // remove winner
        }
        __syncthreads();
    }

    for (int t = tid; t < Cc * KTOP; t += 256) {
        int c = t / KTOP;
        int i = t - c * KTOP;
        int idx = sidx[i];
        oprop[n * Cc * KTOP + c * KTOP + i] = x[((size_t)n * Cc + c) * Pp + idx];
        opos [n * Cc * KTOP + c * KTOP + i] = pos[(size_t)c * Pp + idx];
    }
}

// ---------------------------------------------------------------------------
extern "C" void kernel_launch(void* const* d_in, const int* in_sizes, int n_in,
                              void* d_out, int out_size, void* d_ws, size_t ws_size,
                              hipStream_t stream)
{
    const float* x   = (const float*)d_in[0];
    const float* pos = (const float*)d_in[1];
    const float* w1  = (const float*)d_in[2];
    const float* b1  = (const float*)d_in[3];
    const float* w2  = (const float*)d_in[4];
    const float* b2  = (const float*)d_in[5];

    float* out    = (float*)d_out;
    float* oprop  = out;                                         // (8,256,100)
    float* oposE  = out + (size_t)NBATCH * Cc * KTOP;            // (8,256,100)
    float* logits = out + (size_t)2 * NBATCH * Cc * KTOP;        // (8,81,100,152)

    // workspace layout (floats): hid | pmap | cmap | scores
    float* ws     = (float*)d_ws;
    float* hid    = ws;                                          // 8*256*15200
    float* pmap   = ws + (size_t)NBATCH * Cc * Pp;               // 8*15200
    int*   cmap   = (int*)(pmap + (size_t)NBATCH * Pp);          // 8*15200
    float* scores = (float*)(cmap + (size_t)NBATCH * Pp);        // 8*15200

    conv3x3_relu<<<dim3((Pp + BN - 1) / BN, Cc / BM, NBATCH), 256, 0, stream>>>(
        x, w1, b1, hid);
    conv1x1_softmax<<<dim3((Pp + 255) / 256, NBATCH), 256, 0, stream>>>(
        hid, w2, b2, logits, pmap, cmap);
    local_score<<<dim3((Pp + 255) / 256, NBATCH), 256, 0, stream>>>(
        pmap, cmap, scores);
    topk_gather<<<NBATCH, 256, 0, stream>>>(scores, x, pos, oprop, oposE);
}

// Round 2
// 2597.716 us; speedup vs baseline: 1.1522x; 1.1522x over previous
//
#include <hip/hip_runtime.h>

// Problem constants
#define Hh    100
#define Ww    152
#define Pp    15200        // H*W
#define Cc    256
#define NBATCH 8
#define NC1   81
#define NCLS  80
#define KTOP  100

// conv tile
#define BM 128
#define BN 128

// B-tile LDS swizzle (float4 granularity): spreads stride-2-float4 lane
// addresses from 4 bank-groups (4-way) to 8 groups (2-way = free).
__device__ __forceinline__ int swz(int L) { return L ^ ((L >> 3) & 1); }

// ---------------------------------------------------------------------------
// Kernel 0: one-time transpose w1 [k][c*9+t] -> w1t [c*9+t][k] so conv A-tile
// staging has coalesced global loads AND conflict-free LDS stores.
// ---------------------------------------------------------------------------
__global__ void transpose_w1(const float* __restrict__ w1, float* __restrict__ w1t)
{
    int ct = blockIdx.x;        // 0..2303
    int k  = threadIdx.x;       // 0..255
    w1t[ct * 256 + k] = w1[k * 2304 + ct];
}

// ---------------------------------------------------------------------------
// Kernel 1: 3x3 conv (SAME, stride 1) + bias + ReLU.
// Implicit GEMM: 128 out-ch x 128 flat pixels per block, BK=8 in-ch chunks,
// 9 taps inner. Per-thread 8x8 accumulators (ty: k-group, tx: pixel-group).
// B tile: 4 full rows (y0-1..y0+2) x 152 stored flat per channel (XOR-swizzled
// at float4 granularity); x-borders fixed by hoisted predicates.
// ---------------------------------------------------------------------------
__global__ __launch_bounds__(256, 2)
void conv3x3_relu(const float* __restrict__ x, const float* __restrict__ w1t,
                  const float* __restrict__ b1, float* __restrict__ hid)
{
    __shared__ float As[72 * 128];      // [ct = c_l*9+tap][k]
    __shared__ float Bs[4880];          // swizzled float4 space, 1218 chunks used

    const int tid = threadIdx.x;
    const int p0  = blockIdx.x * BN;
    const int k0  = blockIdx.y * BM;
    const int n   = blockIdx.z;
    const int y0  = p0 / Ww;
    const int tx  = tid & 15;           // pixel group (8 px each)
    const int ty  = tid >> 4;           // out-channel group (8 k each)
    const int pl  = (p0 - y0 * Ww) + tx * 8;  // flat offset rel. to row y0 start
    const int plq = pl >> 2;            // float4 units (pl % 8 == 0)

    // x-coordinate of this thread's first pixel; border slots
    const int xs   = (p0 + tx * 8) % Ww;
    const int j0   = (Ww - xs) % Ww;    // slot with x==0   (valid if <8)
    const int j151 = (Ww - 1) - xs;     // slot with x==151 (valid if <8)
    bool z0[8], z1[8];
#pragma unroll
    for (int j = 0; j < 8; ++j) { z0[j] = (j == j0); z1[j] = (j == j151); }

    float acc[8][8];
#pragma unroll
    for (int a = 0; a < 8; ++a)
#pragma unroll
        for (int b = 0; b < 8; ++b) acc[a][b] = 0.f;

    const size_t xbase = (size_t)n * Cc * Pp;

#pragma unroll 1
    for (int c0 = 0; c0 < Cc; c0 += 8) {
        // ---- stage A from w1t: 72 rows (ct) x 128 k = 2304 float4 ----
#pragma unroll
        for (int i = 0; i < 9; ++i) {
            int q   = i * 256 + tid;    // float4 id
            int row = q >> 5;           // 32 float4 per row
            int c4  = q & 31;
            float4 v = *(const float4*)(w1t + ((size_t)(c0 * 9 + row) * 256) + k0 + c4 * 4);
            *(float4*)(&As[row * 128 + c4 * 4]) = v;
        }
        // ---- stage B: rows y0-1..y0+2, 152 cols, 8 channels (1216 float4) ----
#pragma unroll
        for (int i = 0; i < 5; ++i) {
            int q = i * 256 + tid;
            if (q < 1216) {
                int cr = q / 38;
                int f  = q - cr * 38;
                int cl = cr >> 2;
                int ry = cr & 3;
                int y  = y0 - 1 + ry;
                float4 v = make_float4(0.f, 0.f, 0.f, 0.f);
                if ((unsigned)y < (unsigned)Hh)
                    v = *(const float4*)(x + xbase + (size_t)(c0 + cl) * Pp + y * Ww + f * 4);
                int L = 1 + cl * 152 + ry * 38 + f;   // +1: one-chunk front pad
                *(float4*)(&Bs[swz(L) * 4]) = v;
            }
        }
        __syncthreads();

        // ---- compute ----
#pragma unroll 1
        for (int cl = 0; cl < 8; ++cl) {
#pragma unroll
            for (int dy = 0; dy < 3; ++dy) {
                // 16-float window covering all 3 dx shifts of this row
                int Lb = cl * 152 + dy * 38 + plq;    // logical float4 index
                float4 q0 = *(const float4*)(&Bs[swz(Lb    ) * 4]);
                float4 q1 = *(const float4*)(&Bs[swz(Lb + 1) * 4]);
                float4 q2 = *(const float4*)(&Bs[swz(Lb + 2) * 4]);
                float4 q3 = *(const float4*)(&Bs[swz(Lb + 3) * 4]);
                float r[16] = {q0.x,q0.y,q0.z,q0.w, q1.x,q1.y,q1.z,q1.w,
                               q2.x,q2.y,q2.z,q2.w, q3.x,q3.y,q3.z,q3.w};
                const float* ap = &As[(cl * 9 + dy * 3) * 128 + ty * 8];
#pragma unroll
                for (int dx = 0; dx < 3; ++dx) {
                    float4 a0 = *(const float4*)(ap + dx * 128);
                    float4 a1 = *(const float4*)(ap + dx * 128 + 4);
                    float a[8] = {a0.x,a0.y,a0.z,a0.w, a1.x,a1.y,a1.z,a1.w};
                    float b[8];
#pragma unroll
                    for (int j = 0; j < 8; ++j) {
                        float v = r[3 + j + dx];
                        if (dx == 0) v = z0[j] ? 0.f : v;   // x==0  : left neighbor OOB
                        if (dx == 2) v = z1[j] ? 0.f : v;   // x==151: right neighbor OOB
                        b[j] = v;
                    }
#pragma unroll
                    for (int ko = 0; ko < 8; ++ko)
#pragma unroll
                        for (int j = 0; j < 8; ++j)
                            acc[ko][j] = fmaf(a[ko], b[j], acc[ko][j]);
                }
            }
        }
        __syncthreads();
    }

    // ---- epilogue: bias + relu, float4 stores ----
    if (p0 + tx * 8 < Pp) {
#pragma unroll
        for (int ko = 0; ko < 8; ++ko) {
            int k = k0 + ty * 8 + ko;
            float bias = b1[k];
            float4 v0, v1;
            v0.x = fmaxf(acc[ko][0] + bias, 0.f);
            v0.y = fmaxf(acc[ko][1] + bias, 0.f);
            v0.z = fmaxf(acc[ko][2] + bias, 0.f);
            v0.w = fmaxf(acc[ko][3] + bias, 0.f);
            v1.x = fmaxf(acc[ko][4] + bias, 0.f);
            v1.y = fmaxf(acc[ko][5] + bias, 0.f);
            v1.z = fmaxf(acc[ko][6] + bias, 0.f);
            v1.w = fmaxf(acc[ko][7] + bias, 0.f);
            float* dst = hid + ((size_t)n * Cc + k) * Pp + p0 + tx * 8;
            *(float4*)dst = v0;
            *(float4*)(dst + 4) = v1;
        }
    }
}

// ---------------------------------------------------------------------------
// Kernel 2: 1x1 conv to 81 logits + bias, softmax over 81, argmax over 80.
// Writes logits (output 2) and per-pixel (p = prob of argmax class, c) maps.
// ---------------------------------------------------------------------------
__global__ __launch_bounds__(256, 2)
void conv1x1_softmax(const float* __restrict__ hid, const float* __restrict__ w2,
                     const float* __restrict__ b2, float* __restrict__ logits,
                     float* __restrict__ pmap, int* __restrict__ cmap)
{
    __shared__ float w2s[64 * 84];   // [c_l][j], j padded 81->84 with zeros
    const int tid = threadIdx.x;
    const int p   = blockIdx.x * 256 + tid;
    const int n   = blockIdx.y;
    const bool valid = (p < Pp);
    const int psafe = valid ? p : 0;

    float acc[84];
#pragma unroll
    for (int j = 0; j < 84; ++j) acc[j] = 0.f;

#pragma unroll 1
    for (int c0 = 0; c0 < Cc; c0 += 64) {
        __syncthreads();
#pragma unroll
        for (int i = 0; i < 21; ++i) {   // 21*256 == 64*84
            int q  = i * 256 + tid;
            int cl = q / 84;
            int j  = q - cl * 84;
            float v = 0.f;
            if (j < NC1) v = w2[j * 256 + c0 + cl];
            w2s[cl * 84 + j] = v;
        }
        __syncthreads();

        const float* hptr = hid + ((size_t)n * Cc + c0) * Pp + psafe;
#pragma unroll 2
        for (int cl = 0; cl < 64; ++cl) {
            float h = hptr[(size_t)cl * Pp];
            const float4* wrow = (const float4*)(&w2s[cl * 84]);
#pragma unroll
            for (int f = 0; f < 21; ++f) {
                float4 wv = wrow[f];
                acc[f * 4 + 0] = fmaf(wv.x, h, acc[f * 4 + 0]);
                acc[f * 4 + 1] = fmaf(wv.y, h, acc[f * 4 + 1]);
                acc[f * 4 + 2] = fmaf(wv.z, h, acc[f * 4 + 2]);
                acc[f * 4 + 3] = fmaf(wv.w, h, acc[f * 4 + 3]);
            }
        }
    }

    if (valid) {
#pragma unroll
        for (int j = 0; j < NC1; ++j) acc[j] += b2[j];

        float* lp = logits + (size_t)n * NC1 * Pp + p;
#pragma unroll
        for (int j = 0; j < NC1; ++j) lp[(size_t)j * Pp] = acc[j];

        float m = -3.4e38f;
#pragma unroll
        for (int j = 0; j < NC1; ++j) m = fmaxf(m, acc[j]);
        float s = 0.f;
#pragma unroll
        for (int j = 0; j < NC1; ++j) s += __expf(acc[j] - m);
        float best = -3.4e38f; int bi = 0;
#pragma unroll
        for (int j = 0; j < NCLS; ++j) {   // first occurrence wins (strict >)
            if (acc[j] > best) { best = acc[j]; bi = j; }
        }
        pmap[n * Pp + p] = __expf(best - m) / s;
        cmap[n * Pp + p] = bi;
    }
}

// ---------------------------------------------------------------------------
// Kernel 3: score = p + 1{local max}. Only the argmax channel is nonzero at
// each pixel, so 81-ch local-max reduces to: no 8-neighbor with same class
// and strictly larger p (and p >= eps).
// ---------------------------------------------------------------------------
__global__ void local_score(const float* __restrict__ pmap, const int* __restrict__ cmap,
                            float* __restrict__ scores)
{
    int p = blockIdx.x * 256 + threadIdx.x;
    int n = blockIdx.y;
    if (p >= Pp) return;
    int base = n * Pp;
    float pv = pmap[base + p];
    int   c  = cmap[base + p];
    int y = p / Ww, xc = p - y * Ww;
    bool ok = (pv >= 1e-6f);
#pragma unroll
    for (int dy = -1; dy <= 1; ++dy)
#pragma unroll
        for (int dx = -1; dx <= 1; ++dx) {
            if (dy == 0 && dx == 0) continue;
            int yy = y + dy, xx = xc + dx;
            if (yy >= 0 && yy < Hh && xx >= 0 && xx < Ww) {
                int q = base + yy * Ww + xx;
                if (cmap[q] == c && pmap[q] > pv) ok = false;
            }
        }
    scores[base + p] = pv + (ok ? 1.f : 0.f);
}

// ---------------------------------------------------------------------------
// Kernel 4: per-batch top-100 (lax.top_k semantics: value desc, index asc on
// ties) via 100 iterations of block-wide max over LDS-resident scores, using
// composite key (float_bits << 32) | (0xFFFF - idx). Then gathers x / pos.
// ---------------------------------------------------------------------------
__global__ __launch_bounds__(256)
void topk_gather(const float* __restrict__ scores, const float* __restrict__ x,
                 const float* __restrict__ pos, float* __restrict__ oprop,
                 float* __restrict__ opos)
{
    __shared__ float sv[Pp];                 // 60.8 KB
    __shared__ int sidx[KTOP];
    __shared__ unsigned long long red[4];
    const int tid = threadIdx.x;
    const int n   = blockIdx.x;

    for (int i = tid; i < Pp; i += 256) sv[i] = scores[n * Pp + i];
    __syncthreads();

    for (int it = 0; it < KTOP; ++it) {
        unsigned long long best = 0ull;
        for (int i = tid; i < Pp; i += 256) {
            unsigned fb = __float_as_uint(sv[i]);   // scores > 0 => monotone bits
            unsigned long long key =
                ((unsigned long long)fb << 32) | (unsigned)(0xFFFF - i);
            best = key > best ? key : best;
        }
#pragma unroll
        for (int off = 32; off > 0; off >>= 1) {
            unsigned long long o = __shfl_down(best, off, 64);
            best = o > best ? o : best;
        }
        if ((tid & 63) == 0) red[tid >> 6] = best;
        __syncthreads();
        if (tid == 0) {
            unsigned long long b = red[0];
            b = red[1] > b ? red[1] : b;
            b = red[2] > b ? red[2] : b;
            b = red[3] > b ? red[3] : b;
            int idx = 0xFFFF - (int)(b & 0xFFFFFFFFull);
            sidx[it] = idx;
            sv[idx]  = 0.f;                  // remove winner
        }
        __syncthreads();
    }

    for (int t = tid; t < Cc * KTOP; t += 256) {
        int c = t / KTOP;
        int i = t - c * KTOP;
        int idx = sidx[i];
        oprop[n * Cc * KTOP + c * KTOP + i] = x[((size_t)n * Cc + c) * Pp + idx];
        opos [n * Cc * KTOP + c * KTOP + i] = pos[(size_t)c * Pp + idx];
    }
}

// ---------------------------------------------------------------------------
extern "C" void kernel_launch(void* const* d_in, const int* in_sizes, int n_in,
                              void* d_out, int out_size, void* d_ws, size_t ws_size,
                              hipStream_t stream)
{
    const float* x   = (const float*)d_in[0];
    const float* pos = (const float*)d_in[1];
    const float* w1  = (const float*)d_in[2];
    const float* b1  = (const float*)d_in[3];
    const float* w2  = (const float*)d_in[4];
    const float* b2  = (const float*)d_in[5];

    float* out    = (float*)d_out;
    float* oprop  = out;                                         // (8,256,100)
    float* oposE  = out + (size_t)NBATCH * Cc * KTOP;            // (8,256,100)
    float* logits = out + (size_t)2 * NBATCH * Cc * KTOP;        // (8,81,100,152)

    // w1t (2304x256 floats = 2.36 MB) borrows the logits region of d_out:
    // written before conv3x3, consumed by conv3x3, overwritten by conv1x1.
    float* w1t = logits;

    // workspace layout (floats): hid | pmap | cmap | scores
    float* ws     = (float*)d_ws;
    float* hid    = ws;                                          // 8*256*15200
    float* pmap   = ws + (size_t)NBATCH * Cc * Pp;               // 8*15200
    int*   cmap   = (int*)(pmap + (size_t)NBATCH * Pp);          // 8*15200
    float* scores = (float*)(cmap + (size_t)NBATCH * Pp);        // 8*15200

    transpose_w1<<<2304, 256, 0, stream>>>(w1, w1t);
    conv3x3_relu<<<dim3((Pp + BN - 1) / BN, Cc / BM, NBATCH), 256, 0, stream>>>(
        x, w1t, b1, hid);
    conv1x1_softmax<<<dim3((Pp + 255) / 256, NBATCH), 256, 0, stream>>>(
        hid, w2, b2, logits, pmap, cmap);
    local_score<<<dim3((Pp + 255) / 256, NBATCH), 256, 0, stream>>>(
        pmap, cmap, scores);
    topk_gather<<<NBATCH, 256, 0, stream>>>(scores, x, pos, oprop, oposE);
}